// Round 19
// baseline (289.809 us; speedup 1.0000x reference)
//
#include <hip/hip_runtime.h>

// GCN: 3x (linear -> symmetric-norm conv -> bias -> tanh) -> linear.
// N=200000, E=3200000, F=256->32->16->8->4, fp32 in/out.
// Round 19: round-16 base (best measured: 256us; MFMA linear1 w/ in-kernel W
// pack, BSH=10 CSR, csrb@512) + gathers deepened to 16 outstanding edge
// loads per lane (avg degree 16 => one latency round-trip per node, was two).
// Algebra: norm = dinv[s]*dinv[d]  =>  agg_i = dinv_i * (hs_i + sum_in hs_src)
// with hs = (h @ W) * dinv folded into the producing kernel's epilogue.

constexpr int F_IN = 256;
constexpr int BSH = 10;            // nodes per coarse bucket = 1024
constexpr int BN  = 1 << BSH;
constexpr int CH  = 8192;          // edges per chunk
constexpr int SRC_BITS = 18;       // N=200000 < 2^18; 10+18=28 bits
constexpr int SRC_MASK = (1 << SRC_BITS) - 1;

typedef short short8 __attribute__((ext_vector_type(8)));   // 8 bf16 (4 VGPR)
typedef float f32x4 __attribute__((ext_vector_type(4)));

// ---- bf16 helpers (RNE) ----
__device__ __forceinline__ float bf2f(unsigned short u) {
    return __uint_as_float(((unsigned int)u) << 16);
}
__device__ __forceinline__ unsigned short f2bf(float f) {
    unsigned int u = __float_as_uint(f);
    u += 0x7FFFu + ((u >> 16) & 1u);
    return (unsigned short)(u >> 16);
}
__device__ __forceinline__ unsigned int pack2(float a, float b) {
    return (unsigned int)f2bf(a) | ((unsigned int)f2bf(b) << 16);
}
__device__ __forceinline__ float4 up4(uint2 v) {
    return make_float4(bf2f((unsigned short)(v.x & 0xFFFF)),
                       bf2f((unsigned short)(v.x >> 16)),
                       bf2f((unsigned short)(v.y & 0xFFFF)),
                       bf2f((unsigned short)(v.y >> 16)));
}

// ---- pass A1: per-chunk bucket histogram (transposed store: hist[b][c]) ----
__global__ void histc_kernel(const int* __restrict__ dst, int* __restrict__ hist,
                             int NB_C, int nch, int E) {
    __shared__ int h[256];
    const int t = threadIdx.x, c = blockIdx.x;
    h[t] = 0; __syncthreads();
    const int e0 = c * CH, e1 = min(e0 + CH, E);
    for (int e = e0 + t; e < e1; e += 256)
        atomicAdd(&h[dst[e] >> BSH], 1);
    __syncthreads();
    if (t < NB_C) hist[(size_t)t * nch + c] = h[t];
}

// ---- pass A2: exclusive scan of each bucket row (in place), total -> btotal ----
__global__ void scanb_kernel(int* __restrict__ hist, int* __restrict__ btotal, int nch) {
    __shared__ int s[256];
    const int b = blockIdx.x, t = threadIdx.x;
    int* row = hist + (size_t)b * nch;
    const int K = (nch + 255) / 256;
    int loc[8]; int tot = 0;
    for (int i = 0; i < K; ++i) {
        int idx = t * K + i;
        int v = (idx < nch) ? row[idx] : 0;
        loc[i] = tot; tot += v;
    }
    s[t] = tot; const int own = tot; __syncthreads();
    for (int off = 1; off < 256; off <<= 1) {
        int a = (t >= off) ? s[t - off] : 0; __syncthreads();
        s[t] += a; __syncthreads();
    }
    const int excl = s[t] - own;
    for (int i = 0; i < K; ++i) {
        int idx = t * K + i;
        if (idx < nch) row[idx] = excl + loc[i];
    }
    if (t == 255) btotal[b] = s[255];
}

// ---- pass A3: exclusive scan of bucket totals -> colbase[NB_C+1] ----
__global__ void scanc_kernel(const int* __restrict__ btotal, int* __restrict__ colbase, int NB_C) {
    __shared__ int s[256];
    const int t = threadIdx.x;
    int v = (t < NB_C) ? btotal[t] : 0;
    s[t] = v; const int own = v; __syncthreads();
    for (int off = 1; off < 256; off <<= 1) {
        int a = (t >= off) ? s[t - off] : 0; __syncthreads();
        s[t] += a; __syncthreads();
    }
    if (t < NB_C) colbase[t] = s[t] - own;
    if (t == 255) colbase[NB_C] = s[255];
}

// ---- pass A4: scatter packed (local_dst<<18)|src to exact slots ----
__global__ void scat_kernel(const int* __restrict__ src, const int* __restrict__ dst,
                            const int* __restrict__ hist, const int* __restrict__ colbase,
                            int* __restrict__ pairs, int NB_C, int nch, int E) {
    __shared__ int cur[256];
    const int t = threadIdx.x, c = blockIdx.x;
    if (t < NB_C) cur[t] = colbase[t] + hist[(size_t)t * nch + c];
    __syncthreads();
    const int e0 = c * CH, e1 = min(e0 + CH, E);
    for (int e = e0 + t; e < e1; e += 256) {
        int d = dst[e];
        int b = d >> BSH;
        int p = atomicAdd(&cur[b], 1);
        pairs[p] = ((d & (BN - 1)) << SRC_BITS) | src[e];
    }
}

// ---- pass B: per-bucket CSR build, 512 threads (block = 1024-node bucket) ----
__global__ __launch_bounds__(512) void csrb_kernel(const int* __restrict__ pairs,
                                                   const int* __restrict__ colbase,
                                                   int* __restrict__ cnt, int* __restrict__ rowptr,
                                                   float* __restrict__ dinv, int* __restrict__ list,
                                                   int N) {
    __shared__ int deg[BN];
    __shared__ int lex[BN];
    __shared__ int s[512];
    const int b = blockIdx.x, t = threadIdx.x;
    const int n0 = b << BSH;
    const int g0 = colbase[b], g1 = colbase[b + 1];
    for (int i = t; i < BN; i += 512) deg[i] = 0;
    __syncthreads();
    for (int i = g0 + t; i < g1; i += 512)
        atomicAdd(&deg[pairs[i] >> SRC_BITS], 1);
    __syncthreads();
    const int b2 = t * 2;
    const int l0 = deg[b2], l1 = deg[b2 + 1];
    const int tot = l0 + l1;
    s[t] = tot; const int own = tot; __syncthreads();
    for (int off = 1; off < 512; off <<= 1) {
        int a = (t >= off) ? s[t - off] : 0; __syncthreads();
        s[t] += a; __syncthreads();
    }
    const int excl = s[t] - own;
    lex[b2] = excl; lex[b2 + 1] = excl + l0;
#pragma unroll
    for (int k = 0; k < 2; ++k) {
        int n = n0 + b2 + k;
        if (n < N) {
            int dg = deg[b2 + k];
            cnt[n] = dg;
            rowptr[n] = g0 + lex[b2 + k];
            dinv[n] = rsqrtf((float)dg + 1.0f);
        }
    }
    __syncthreads();
    for (int i = t; i < BN; i += 512) deg[i] = 0;   // reuse as cursors
    __syncthreads();
    for (int i = g0 + t; i < g1; i += 512) {
        int pr = pairs[i];
        int ld = pr >> SRC_BITS;
        int p = lex[ld] + atomicAdd(&deg[ld], 1);
        list[g0 + p] = pr & SRC_MASK;
    }
}

// ---------------- layer-1 GEMM (MFMA): hs = (x @ W) * dinv -> BF16 ----------------
// BM=128 (4 waves x 32 rows), BK=64 dbuf. xs bf16 [2][128][72]; W packed
// once/block into LDS B-frags (16KB). Per wave: 2Mt x 2Nt, 8 K-steps.
__global__ __launch_bounds__(256) void linear1_kernel(const float* __restrict__ x,
                                                      const float* __restrict__ W,
                                                      const float* __restrict__ dinv,
                                                      unsigned short* __restrict__ out, int N) {
    constexpr int PITCH = 72;
    __shared__ unsigned short xs[2][128][PITCH];     // 36,864 B
    __shared__ unsigned short Ws[8 * 2 * 64 * 8];    // 16,384 B
    const int t = threadIdx.x;
    const int w = t >> 6;              // wave 0..3
    const int lane = t & 63;
    const long row0 = (long)blockIdx.x * 128;

    float4 xst[8];

    auto issue = [&](int kc) {         // load next x chunk: 128 rows x 64 k fp32
#pragma unroll
        for (int i = 0; i < 8; ++i) {
            const int id = i * 256 + t;
            const int r = id >> 4, f4 = id & 15;
            const long gr = row0 + r;
            xst[i] = (gr < N) ? *(const float4*)(x + gr * F_IN + kc * 64 + f4 * 4)
                              : make_float4(0.f, 0.f, 0.f, 0.f);
        }
    };
    auto write_buf = [&](int p) {      // fp32 -> bf16, ds_write_b64
#pragma unroll
        for (int i = 0; i < 8; ++i) {
            const int id = i * 256 + t;
            const int r = id >> 4, f4 = id & 15;
            uint2 v;
            v.x = pack2(xst[i].x, xst[i].y);
            v.y = pack2(xst[i].z, xst[i].w);
            *(uint2*)&xs[p][r][f4 * 4] = v;
        }
    };

    issue(0);
    // ---- pack W into B-fragments (once per block) ----
#pragma unroll
    for (int e = 0; e < 4; ++e) {
        const int id = e * 256 + t;            // 0..1023
        const int ks = id >> 7;                // 0..7
        const int nt = (id >> 6) & 1;
        const int ln = id & 63;
        const int k0 = ks * 32 + (ln >> 4) * 8;
        const int col = nt * 16 + (ln & 15);
        unsigned int pk[4];
#pragma unroll
        for (int jj = 0; jj < 4; ++jj) {
            float a = W[(k0 + jj * 2 + 0) * 32 + col];
            float b = W[(k0 + jj * 2 + 1) * 32 + col];
            pk[jj] = pack2(a, b);
        }
        *(uint4*)&Ws[((ks * 2 + nt) * 64 + ln) * 8] = make_uint4(pk[0], pk[1], pk[2], pk[3]);
    }
    write_buf(0);
    __syncthreads();

    f32x4 acc[2][2] = {};
    int p = 0;
    for (int kc = 0; kc < 4; ++kc, p ^= 1) {
        if (kc < 3) issue(kc + 1);             // next chunk in flight
#pragma unroll
        for (int ks2 = 0; ks2 < 2; ++ks2) {
            const int ksg = kc * 2 + ks2;      // global K-step 0..7
            short8 a[2], b[2];
#pragma unroll
            for (int mt = 0; mt < 2; ++mt) {
                const int r = w * 32 + mt * 16 + (lane & 15);
                const int ko = ks2 * 32 + (lane >> 4) * 8;
                a[mt] = *(short8*)&xs[p][r][ko];
            }
#pragma unroll
            for (int nt = 0; nt < 2; ++nt)
                b[nt] = *(short8*)&Ws[((ksg * 2 + nt) * 64 + lane) * 8];
#pragma unroll
            for (int mt = 0; mt < 2; ++mt)
#pragma unroll
                for (int nt = 0; nt < 2; ++nt)
                    acc[mt][nt] = __builtin_amdgcn_mfma_f32_16x16x32_bf16(
                        a[mt], b[nt], acc[mt][nt], 0, 0, 0);
        }
        if (kc < 3) write_buf(p ^ 1);          // readers are on buf[p]
        __syncthreads();
    }

    // ---- epilogue: C layout col=lane&15, row=(lane>>4)*4+r ----
    const int col = lane & 15;
    const int rbase = (lane >> 4) * 4;
#pragma unroll
    for (int mt = 0; mt < 2; ++mt) {
#pragma unroll
        for (int r = 0; r < 4; ++r) {
            const long grow = row0 + w * 32 + mt * 16 + rbase + r;
            if (grow >= N) continue;
            const float dv = dinv[grow];
#pragma unroll
            for (int nt = 0; nt < 2; ++nt)
                out[grow * 32 + nt * 16 + col] = f2bf(acc[mt][nt][r] * dv);
        }
    }
}

// ---- 16-deep accumulate helper over uint2 gathers ----
#define GATH16(EXPR_IDX)                                                        \
    do {                                                                        \
        uint2 uu[16];                                                           \
        _Pragma("unroll")                                                       \
        for (int q = 0; q < 16; ++q) uu[q] = hsv[(long)lp[j + q] * (EXPR_IDX) + lane]; \
        _Pragma("unroll")                                                       \
        for (int q = 0; q < 16; ++q) {                                          \
            float4 v = up4(uu[q]);                                              \
            acc.x += v.x; acc.y += v.y; acc.z += v.z; acc.w += v.w;             \
        }                                                                       \
    } while (0)

// ---- gather D=32 (bf16 hs) + fused linear2 -> bf16 out[N][16] ----
__global__ void gather32_lin2_kernel(const int* __restrict__ rowptr, const int* __restrict__ cnt,
                                     const int* __restrict__ list,
                                     const unsigned short* __restrict__ hs,
                                     const float* __restrict__ dinv, const float* __restrict__ b1,
                                     const float* __restrict__ W2,
                                     unsigned short* __restrict__ out, int N) {
    __shared__ float W2s[32][16];
    const int t = threadIdx.x;
    if (t < 128) ((float4*)&W2s[0][0])[t] = ((const float4*)W2)[t];
    __syncthreads();
    const int g = t >> 3, lane = t & 7;
    long node = (long)blockIdx.x * 32 + g;
    if (node >= N) return;
    const int start = rowptr[node];
    const int num = cnt[node];
    const int* __restrict__ lp = list + start;
    const uint2* __restrict__ hsv = (const uint2*)hs;
    const int L = 8;
    float4 acc = up4(hsv[node * L + lane]);
    int j = 0;
    for (; j + 16 <= num; j += 16) GATH16(L);
    for (; j < num; ++j) {
        float4 v = up4(hsv[(long)lp[j] * L + lane]);
        acc.x += v.x; acc.y += v.y; acc.z += v.z; acc.w += v.w;
    }
    const float dv = dinv[node];
    const float4 bb = *(const float4*)(b1 + lane * 4);
    float4 h;
    h.x = tanhf(acc.x * dv + bb.x);
    h.y = tanhf(acc.y * dv + bb.y);
    h.z = tanhf(acc.z * dv + bb.z);
    h.w = tanhf(acc.w * dv + bb.w);
    const int c0 = lane * 2;
    float o0 = 0.f, o1 = 0.f;
#pragma unroll
    for (int gk = 0; gk < 8; ++gk) {
        const float a0 = __shfl(h.x, gk, 8);
        const float a1 = __shfl(h.y, gk, 8);
        const float a2 = __shfl(h.z, gk, 8);
        const float a3 = __shfl(h.w, gk, 8);
        o0 += a0 * W2s[gk * 4 + 0][c0] + a1 * W2s[gk * 4 + 1][c0]
            + a2 * W2s[gk * 4 + 2][c0] + a3 * W2s[gk * 4 + 3][c0];
        o1 += a0 * W2s[gk * 4 + 0][c0 + 1] + a1 * W2s[gk * 4 + 1][c0 + 1]
            + a2 * W2s[gk * 4 + 2][c0 + 1] + a3 * W2s[gk * 4 + 3][c0 + 1];
    }
    *(unsigned int*)(out + node * 16 + c0) = pack2(o0 * dv, o1 * dv);
}

// ---- gather D=16 (bf16) + fused linear3 -> bf16 out[N][8] ----
__global__ void gather16_lin3_kernel(const int* __restrict__ rowptr, const int* __restrict__ cnt,
                                     const int* __restrict__ list,
                                     const unsigned short* __restrict__ hs,
                                     const float* __restrict__ dinv, const float* __restrict__ b2,
                                     const float* __restrict__ W3,
                                     unsigned short* __restrict__ out, int N) {
    __shared__ float W3s[16][8];
    const int t = threadIdx.x;
    if (t < 32) ((float4*)&W3s[0][0])[t] = ((const float4*)W3)[t];
    __syncthreads();
    const int g = t >> 2, lane = t & 3;
    long node = (long)blockIdx.x * 64 + g;
    if (node >= N) return;
    const int start = rowptr[node];
    const int num = cnt[node];
    const int* __restrict__ lp = list + start;
    const uint2* __restrict__ hsv = (const uint2*)hs;
    const int L = 4;
    float4 acc = up4(hsv[node * L + lane]);
    int j = 0;
    for (; j + 16 <= num; j += 16) GATH16(L);
    for (; j < num; ++j) {
        float4 v = up4(hsv[(long)lp[j] * L + lane]);
        acc.x += v.x; acc.y += v.y; acc.z += v.z; acc.w += v.w;
    }
    const float dv = dinv[node];
    const float4 bb = *(const float4*)(b2 + lane * 4);
    float4 h;
    h.x = tanhf(acc.x * dv + bb.x);
    h.y = tanhf(acc.y * dv + bb.y);
    h.z = tanhf(acc.z * dv + bb.z);
    h.w = tanhf(acc.w * dv + bb.w);
    const int c0 = lane * 2;
    float o0 = 0.f, o1 = 0.f;
#pragma unroll
    for (int gk = 0; gk < 4; ++gk) {
        const float a0 = __shfl(h.x, gk, 4);
        const float a1 = __shfl(h.y, gk, 4);
        const float a2 = __shfl(h.z, gk, 4);
        const float a3 = __shfl(h.w, gk, 4);
        o0 += a0 * W3s[gk * 4 + 0][c0] + a1 * W3s[gk * 4 + 1][c0]
            + a2 * W3s[gk * 4 + 2][c0] + a3 * W3s[gk * 4 + 3][c0];
        o1 += a0 * W3s[gk * 4 + 0][c0 + 1] + a1 * W3s[gk * 4 + 1][c0 + 1]
            + a2 * W3s[gk * 4 + 2][c0 + 1] + a3 * W3s[gk * 4 + 3][c0 + 1];
    }
    *(unsigned int*)(out + node * 8 + c0) = pack2(o0 * dv, o1 * dv);
}

// ---- gather D=8 (bf16) + classifier -> fp32 out[N][4] ----
__global__ void gather8_final_kernel(const int* __restrict__ rowptr, const int* __restrict__ cnt,
                                     const int* __restrict__ list,
                                     const unsigned short* __restrict__ hs,
                                     const float* __restrict__ dinv, const float* __restrict__ b,
                                     const float* __restrict__ Wc, const float* __restrict__ bc,
                                     float* __restrict__ out, int N) {
    const int t = threadIdx.x;
    const int g = t >> 1, lane = t & 1;
    long node = (long)blockIdx.x * 128 + g;
    if (node >= N) return;
    const int start = rowptr[node];
    const int num = cnt[node];
    const int* __restrict__ lp = list + start;
    const uint2* __restrict__ hsv = (const uint2*)hs;
    const int L = 2;
    float4 acc = up4(hsv[node * L + lane]);
    int j = 0;
    for (; j + 16 <= num; j += 16) GATH16(L);
    for (; j < num; ++j) {
        float4 v = up4(hsv[(long)lp[j] * L + lane]);
        acc.x += v.x; acc.y += v.y; acc.z += v.z; acc.w += v.w;
    }
    const float dv = dinv[node];
    const float4 bb = *(const float4*)(b + lane * 4);
    float4 h;
    h.x = tanhf(acc.x * dv + bb.x);
    h.y = tanhf(acc.y * dv + bb.y);
    h.z = tanhf(acc.z * dv + bb.z);
    h.w = tanhf(acc.w * dv + bb.w);
    const float4 w0 = *(const float4*)(Wc + (lane * 4 + 0) * 4);
    const float4 w1 = *(const float4*)(Wc + (lane * 4 + 1) * 4);
    const float4 w2 = *(const float4*)(Wc + (lane * 4 + 2) * 4);
    const float4 w3 = *(const float4*)(Wc + (lane * 4 + 3) * 4);
    float4 p;
    p.x = h.x * w0.x + h.y * w1.x + h.z * w2.x + h.w * w3.x;
    p.y = h.x * w0.y + h.y * w1.y + h.z * w2.y + h.w * w3.y;
    p.z = h.x * w0.z + h.y * w1.z + h.z * w2.z + h.w * w3.z;
    p.w = h.x * w0.w + h.y * w1.w + h.z * w2.w + h.w * w3.w;
    p.x += __shfl_xor(p.x, 1);
    p.y += __shfl_xor(p.y, 1);
    p.z += __shfl_xor(p.z, 1);
    p.w += __shfl_xor(p.w, 1);
    if (lane == 0) {
        const float4 bcv = *(const float4*)bc;
        float4 o = make_float4(p.x + bcv.x, p.y + bcv.y, p.z + bcv.z, p.w + bcv.w);
        *(float4*)(out + node * 4) = o;
    }
}

extern "C" void kernel_launch(void* const* d_in, const int* in_sizes, int n_in,
                              void* d_out, int out_size, void* d_ws, size_t ws_size,
                              hipStream_t stream) {
    const float* x  = (const float*)d_in[0];
    const int*   ei = (const int*)d_in[1];
    const float* W1 = (const float*)d_in[2];
    const float* b1 = (const float*)d_in[3];
    const float* W2 = (const float*)d_in[4];
    const float* b2 = (const float*)d_in[5];
    const float* W3 = (const float*)d_in[6];
    const float* b3 = (const float*)d_in[7];
    const float* Wc = (const float*)d_in[8];
    const float* bc = (const float*)d_in[9];
    float* out = (float*)d_out;

    const int N = in_sizes[0] / F_IN;
    const int E = in_sizes[1] / 2;
    const int* src = ei;
    const int* dst = ei + E;
    const int B = 256;

    const int NB_C = (N + BN - 1) >> BSH;       // coarse buckets (196) <= 256
    const int nch  = (E + CH - 1) / CH;         // chunks (391)

    char* p = (char*)d_ws;
    auto take = [&](size_t bytes) { char* q = p; p += (bytes + 255) & ~size_t(255); return q; };
    int*   cnt     = (int*)take((size_t)N * 4);
    int*   rowptr  = (int*)take((size_t)N * 4);
    float* dinv    = (float*)take((size_t)N * 4);
    int*   hist    = (int*)take((size_t)NB_C * nch * 4);
    int*   btotal  = (int*)take((size_t)NB_C * 4);
    int*   colbase = (int*)take((size_t)(NB_C + 1) * 4);
    int*   list    = (int*)take((size_t)E * 4);
    unsigned short* bufA = (unsigned short*)take((size_t)N * 32 * 4);
    unsigned short* bufB = (unsigned short*)take((size_t)N * 32 * 4);
    int*   pairs   = (int*)bufA;   // alias: pairs dead before gather32 writes bufA

    // ---- CSR build (deterministic two-level counting sort, packed pairs) ----
    histc_kernel<<<nch, B, 0, stream>>>(dst, hist, NB_C, nch, E);
    scanb_kernel<<<NB_C, B, 0, stream>>>(hist, btotal, nch);
    scanc_kernel<<<1, B, 0, stream>>>(btotal, colbase, NB_C);
    scat_kernel<<<nch, B, 0, stream>>>(src, dst, hist, colbase, pairs, NB_C, nch, E);
    csrb_kernel<<<NB_C, 512, 0, stream>>>(pairs, colbase, cnt, rowptr, dinv, list, N);

    // ---- layer 1: 256 -> 32 (MFMA, bf16 hs) ----
    linear1_kernel<<<(N + 127) / 128, B, 0, stream>>>(x, W1, dinv, bufB, N);
    // ---- layer 1 conv + layer 2 linear fused (bf16 -> bf16) ----
    gather32_lin2_kernel<<<(N + 31) / 32, B, 0, stream>>>(rowptr, cnt, list, bufB, dinv, b1, W2, bufA, N);
    // ---- layer 2 conv + layer 3 linear fused (bf16 -> bf16) ----
    gather16_lin3_kernel<<<(N + 63) / 64, B, 0, stream>>>(rowptr, cnt, list, bufA, dinv, b2, W3, bufB, N);
    // ---- layer 3 conv + classifier fused (bf16 -> fp32 out) ----
    gather8_final_kernel<<<(N + 127) / 128, B, 0, stream>>>(rowptr, cnt, list, bufB, dinv, b3, Wc, bc, out, N);
}

// Round 20
// 246.541 us; speedup vs baseline: 1.1755x; 1.1755x over previous
//
#include <hip/hip_runtime.h>

// GCN: 3x (linear -> symmetric-norm conv -> bias -> tanh) -> linear.
// N=200000, E=3200000, F=256->32->16->8->4, fp32 in/out.
// Round 20: round-16 base (best measured 256us) + 4-deep tail batch in the
// gathers (round-19's 16-deep failed: Poisson(16) degrees => half the nodes
// fell to the scalar dependent tail; 8-deep + 4-deep tail covers the typical
// remainder ~3.7 with one parallel issue).
// Algebra: norm = dinv[s]*dinv[d]  =>  agg_i = dinv_i * (hs_i + sum_in hs_src)
// with hs = (h @ W) * dinv folded into the producing kernel's epilogue.

constexpr int F_IN = 256;
constexpr int BSH = 10;            // nodes per coarse bucket = 1024
constexpr int BN  = 1 << BSH;
constexpr int CH  = 8192;          // edges per chunk
constexpr int SRC_BITS = 18;       // N=200000 < 2^18; 10+18=28 bits
constexpr int SRC_MASK = (1 << SRC_BITS) - 1;

typedef short short8 __attribute__((ext_vector_type(8)));   // 8 bf16 (4 VGPR)
typedef float f32x4 __attribute__((ext_vector_type(4)));

// ---- bf16 helpers (RNE) ----
__device__ __forceinline__ float bf2f(unsigned short u) {
    return __uint_as_float(((unsigned int)u) << 16);
}
__device__ __forceinline__ unsigned short f2bf(float f) {
    unsigned int u = __float_as_uint(f);
    u += 0x7FFFu + ((u >> 16) & 1u);
    return (unsigned short)(u >> 16);
}
__device__ __forceinline__ unsigned int pack2(float a, float b) {
    return (unsigned int)f2bf(a) | ((unsigned int)f2bf(b) << 16);
}
__device__ __forceinline__ float4 up4(uint2 v) {
    return make_float4(bf2f((unsigned short)(v.x & 0xFFFF)),
                       bf2f((unsigned short)(v.x >> 16)),
                       bf2f((unsigned short)(v.y & 0xFFFF)),
                       bf2f((unsigned short)(v.y >> 16)));
}

// ---- pass A1: per-chunk bucket histogram (transposed store: hist[b][c]) ----
__global__ void histc_kernel(const int* __restrict__ dst, int* __restrict__ hist,
                             int NB_C, int nch, int E) {
    __shared__ int h[256];
    const int t = threadIdx.x, c = blockIdx.x;
    h[t] = 0; __syncthreads();
    const int e0 = c * CH, e1 = min(e0 + CH, E);
    for (int e = e0 + t; e < e1; e += 256)
        atomicAdd(&h[dst[e] >> BSH], 1);
    __syncthreads();
    if (t < NB_C) hist[(size_t)t * nch + c] = h[t];
}

// ---- pass A2: exclusive scan of each bucket row (in place), total -> btotal ----
__global__ void scanb_kernel(int* __restrict__ hist, int* __restrict__ btotal, int nch) {
    __shared__ int s[256];
    const int b = blockIdx.x, t = threadIdx.x;
    int* row = hist + (size_t)b * nch;
    const int K = (nch + 255) / 256;
    int loc[8]; int tot = 0;
    for (int i = 0; i < K; ++i) {
        int idx = t * K + i;
        int v = (idx < nch) ? row[idx] : 0;
        loc[i] = tot; tot += v;
    }
    s[t] = tot; const int own = tot; __syncthreads();
    for (int off = 1; off < 256; off <<= 1) {
        int a = (t >= off) ? s[t - off] : 0; __syncthreads();
        s[t] += a; __syncthreads();
    }
    const int excl = s[t] - own;
    for (int i = 0; i < K; ++i) {
        int idx = t * K + i;
        if (idx < nch) row[idx] = excl + loc[i];
    }
    if (t == 255) btotal[b] = s[255];
}

// ---- pass A3: exclusive scan of bucket totals -> colbase[NB_C+1] ----
__global__ void scanc_kernel(const int* __restrict__ btotal, int* __restrict__ colbase, int NB_C) {
    __shared__ int s[256];
    const int t = threadIdx.x;
    int v = (t < NB_C) ? btotal[t] : 0;
    s[t] = v; const int own = v; __syncthreads();
    for (int off = 1; off < 256; off <<= 1) {
        int a = (t >= off) ? s[t - off] : 0; __syncthreads();
        s[t] += a; __syncthreads();
    }
    if (t < NB_C) colbase[t] = s[t] - own;
    if (t == 255) colbase[NB_C] = s[255];
}

// ---- pass A4: scatter packed (local_dst<<18)|src to exact slots ----
__global__ void scat_kernel(const int* __restrict__ src, const int* __restrict__ dst,
                            const int* __restrict__ hist, const int* __restrict__ colbase,
                            int* __restrict__ pairs, int NB_C, int nch, int E) {
    __shared__ int cur[256];
    const int t = threadIdx.x, c = blockIdx.x;
    if (t < NB_C) cur[t] = colbase[t] + hist[(size_t)t * nch + c];
    __syncthreads();
    const int e0 = c * CH, e1 = min(e0 + CH, E);
    for (int e = e0 + t; e < e1; e += 256) {
        int d = dst[e];
        int b = d >> BSH;
        int p = atomicAdd(&cur[b], 1);
        pairs[p] = ((d & (BN - 1)) << SRC_BITS) | src[e];
    }
}

// ---- pass B: per-bucket CSR build, 512 threads (block = 1024-node bucket) ----
__global__ __launch_bounds__(512) void csrb_kernel(const int* __restrict__ pairs,
                                                   const int* __restrict__ colbase,
                                                   int* __restrict__ cnt, int* __restrict__ rowptr,
                                                   float* __restrict__ dinv, int* __restrict__ list,
                                                   int N) {
    __shared__ int deg[BN];
    __shared__ int lex[BN];
    __shared__ int s[512];
    const int b = blockIdx.x, t = threadIdx.x;
    const int n0 = b << BSH;
    const int g0 = colbase[b], g1 = colbase[b + 1];
    for (int i = t; i < BN; i += 512) deg[i] = 0;
    __syncthreads();
    for (int i = g0 + t; i < g1; i += 512)
        atomicAdd(&deg[pairs[i] >> SRC_BITS], 1);
    __syncthreads();
    const int b2 = t * 2;
    const int l0 = deg[b2], l1 = deg[b2 + 1];
    const int tot = l0 + l1;
    s[t] = tot; const int own = tot; __syncthreads();
    for (int off = 1; off < 512; off <<= 1) {
        int a = (t >= off) ? s[t - off] : 0; __syncthreads();
        s[t] += a; __syncthreads();
    }
    const int excl = s[t] - own;
    lex[b2] = excl; lex[b2 + 1] = excl + l0;
#pragma unroll
    for (int k = 0; k < 2; ++k) {
        int n = n0 + b2 + k;
        if (n < N) {
            int dg = deg[b2 + k];
            cnt[n] = dg;
            rowptr[n] = g0 + lex[b2 + k];
            dinv[n] = rsqrtf((float)dg + 1.0f);
        }
    }
    __syncthreads();
    for (int i = t; i < BN; i += 512) deg[i] = 0;   // reuse as cursors
    __syncthreads();
    for (int i = g0 + t; i < g1; i += 512) {
        int pr = pairs[i];
        int ld = pr >> SRC_BITS;
        int p = lex[ld] + atomicAdd(&deg[ld], 1);
        list[g0 + p] = pr & SRC_MASK;
    }
}

// ---------------- layer-1 GEMM (MFMA): hs = (x @ W) * dinv -> BF16 ----------------
// BM=128 (4 waves x 32 rows), BK=64 dbuf. xs bf16 [2][128][72]; W packed
// once/block into LDS B-frags (16KB). Per wave: 2Mt x 2Nt, 8 K-steps.
__global__ __launch_bounds__(256) void linear1_kernel(const float* __restrict__ x,
                                                      const float* __restrict__ W,
                                                      const float* __restrict__ dinv,
                                                      unsigned short* __restrict__ out, int N) {
    constexpr int PITCH = 72;
    __shared__ unsigned short xs[2][128][PITCH];     // 36,864 B
    __shared__ unsigned short Ws[8 * 2 * 64 * 8];    // 16,384 B
    const int t = threadIdx.x;
    const int w = t >> 6;              // wave 0..3
    const int lane = t & 63;
    const long row0 = (long)blockIdx.x * 128;

    float4 xst[8];

    auto issue = [&](int kc) {         // load next x chunk: 128 rows x 64 k fp32
#pragma unroll
        for (int i = 0; i < 8; ++i) {
            const int id = i * 256 + t;
            const int r = id >> 4, f4 = id & 15;
            const long gr = row0 + r;
            xst[i] = (gr < N) ? *(const float4*)(x + gr * F_IN + kc * 64 + f4 * 4)
                              : make_float4(0.f, 0.f, 0.f, 0.f);
        }
    };
    auto write_buf = [&](int p) {      // fp32 -> bf16, ds_write_b64
#pragma unroll
        for (int i = 0; i < 8; ++i) {
            const int id = i * 256 + t;
            const int r = id >> 4, f4 = id & 15;
            uint2 v;
            v.x = pack2(xst[i].x, xst[i].y);
            v.y = pack2(xst[i].z, xst[i].w);
            *(uint2*)&xs[p][r][f4 * 4] = v;
        }
    };

    issue(0);
    // ---- pack W into B-fragments (once per block) ----
#pragma unroll
    for (int e = 0; e < 4; ++e) {
        const int id = e * 256 + t;            // 0..1023
        const int ks = id >> 7;                // 0..7
        const int nt = (id >> 6) & 1;
        const int ln = id & 63;
        const int k0 = ks * 32 + (ln >> 4) * 8;
        const int col = nt * 16 + (ln & 15);
        unsigned int pk[4];
#pragma unroll
        for (int jj = 0; jj < 4; ++jj) {
            float a = W[(k0 + jj * 2 + 0) * 32 + col];
            float b = W[(k0 + jj * 2 + 1) * 32 + col];
            pk[jj] = pack2(a, b);
        }
        *(uint4*)&Ws[((ks * 2 + nt) * 64 + ln) * 8] = make_uint4(pk[0], pk[1], pk[2], pk[3]);
    }
    write_buf(0);
    __syncthreads();

    f32x4 acc[2][2] = {};
    int p = 0;
    for (int kc = 0; kc < 4; ++kc, p ^= 1) {
        if (kc < 3) issue(kc + 1);             // next chunk in flight
#pragma unroll
        for (int ks2 = 0; ks2 < 2; ++ks2) {
            const int ksg = kc * 2 + ks2;      // global K-step 0..7
            short8 a[2], b[2];
#pragma unroll
            for (int mt = 0; mt < 2; ++mt) {
                const int r = w * 32 + mt * 16 + (lane & 15);
                const int ko = ks2 * 32 + (lane >> 4) * 8;
                a[mt] = *(short8*)&xs[p][r][ko];
            }
#pragma unroll
            for (int nt = 0; nt < 2; ++nt)
                b[nt] = *(short8*)&Ws[((ksg * 2 + nt) * 64 + lane) * 8];
#pragma unroll
            for (int mt = 0; mt < 2; ++mt)
#pragma unroll
                for (int nt = 0; nt < 2; ++nt)
                    acc[mt][nt] = __builtin_amdgcn_mfma_f32_16x16x32_bf16(
                        a[mt], b[nt], acc[mt][nt], 0, 0, 0);
        }
        if (kc < 3) write_buf(p ^ 1);          // readers are on buf[p]
        __syncthreads();
    }

    // ---- epilogue: C layout col=lane&15, row=(lane>>4)*4+r ----
    const int col = lane & 15;
    const int rbase = (lane >> 4) * 4;
#pragma unroll
    for (int mt = 0; mt < 2; ++mt) {
#pragma unroll
        for (int r = 0; r < 4; ++r) {
            const long grow = row0 + w * 32 + mt * 16 + rbase + r;
            if (grow >= N) continue;
            const float dv = dinv[grow];
#pragma unroll
            for (int nt = 0; nt < 2; ++nt)
                out[grow * 32 + nt * 16 + col] = f2bf(acc[mt][nt][r] * dv);
        }
    }
}

// ---- gather D=32 (bf16 hs) + fused linear2 -> bf16 out[N][16] ----
__global__ void gather32_lin2_kernel(const int* __restrict__ rowptr, const int* __restrict__ cnt,
                                     const int* __restrict__ list,
                                     const unsigned short* __restrict__ hs,
                                     const float* __restrict__ dinv, const float* __restrict__ b1,
                                     const float* __restrict__ W2,
                                     unsigned short* __restrict__ out, int N) {
    __shared__ float W2s[32][16];
    const int t = threadIdx.x;
    if (t < 128) ((float4*)&W2s[0][0])[t] = ((const float4*)W2)[t];
    __syncthreads();
    const int g = t >> 3, lane = t & 7;
    long node = (long)blockIdx.x * 32 + g;
    if (node >= N) return;
    const int start = rowptr[node];
    const int num = cnt[node];
    const int* __restrict__ lp = list + start;
    const uint2* __restrict__ hsv = (const uint2*)hs;
    const int L = 8;
    float4 acc = up4(hsv[node * L + lane]);
    int j = 0;
    for (; j + 8 <= num; j += 8) {
        int s0 = lp[j], s1 = lp[j + 1], s2 = lp[j + 2], s3 = lp[j + 3];
        int s4 = lp[j + 4], s5 = lp[j + 5], s6 = lp[j + 6], s7 = lp[j + 7];
        uint2 u0 = hsv[(long)s0 * L + lane], u1 = hsv[(long)s1 * L + lane];
        uint2 u2 = hsv[(long)s2 * L + lane], u3 = hsv[(long)s3 * L + lane];
        uint2 u4 = hsv[(long)s4 * L + lane], u5 = hsv[(long)s5 * L + lane];
        uint2 u6 = hsv[(long)s6 * L + lane], u7 = hsv[(long)s7 * L + lane];
        float4 v0 = up4(u0), v1 = up4(u1), v2 = up4(u2), v3 = up4(u3);
        float4 v4 = up4(u4), v5 = up4(u5), v6 = up4(u6), v7 = up4(u7);
        acc.x += ((v0.x + v1.x) + (v2.x + v3.x)) + ((v4.x + v5.x) + (v6.x + v7.x));
        acc.y += ((v0.y + v1.y) + (v2.y + v3.y)) + ((v4.y + v5.y) + (v6.y + v7.y));
        acc.z += ((v0.z + v1.z) + (v2.z + v3.z)) + ((v4.z + v5.z) + (v6.z + v7.z));
        acc.w += ((v0.w + v1.w) + (v2.w + v3.w)) + ((v4.w + v5.w) + (v6.w + v7.w));
    }
    if (j + 4 <= num) {
        int s0 = lp[j], s1 = lp[j + 1], s2 = lp[j + 2], s3 = lp[j + 3];
        uint2 u0 = hsv[(long)s0 * L + lane], u1 = hsv[(long)s1 * L + lane];
        uint2 u2 = hsv[(long)s2 * L + lane], u3 = hsv[(long)s3 * L + lane];
        float4 v0 = up4(u0), v1 = up4(u1), v2 = up4(u2), v3 = up4(u3);
        acc.x += (v0.x + v1.x) + (v2.x + v3.x);
        acc.y += (v0.y + v1.y) + (v2.y + v3.y);
        acc.z += (v0.z + v1.z) + (v2.z + v3.z);
        acc.w += (v0.w + v1.w) + (v2.w + v3.w);
        j += 4;
    }
    for (; j < num; ++j) {
        float4 v = up4(hsv[(long)lp[j] * L + lane]);
        acc.x += v.x; acc.y += v.y; acc.z += v.z; acc.w += v.w;
    }
    const float dv = dinv[node];
    const float4 bb = *(const float4*)(b1 + lane * 4);
    float4 h;
    h.x = tanhf(acc.x * dv + bb.x);
    h.y = tanhf(acc.y * dv + bb.y);
    h.z = tanhf(acc.z * dv + bb.z);
    h.w = tanhf(acc.w * dv + bb.w);
    const int c0 = lane * 2;
    float o0 = 0.f, o1 = 0.f;
#pragma unroll
    for (int gk = 0; gk < 8; ++gk) {
        const float a0 = __shfl(h.x, gk, 8);
        const float a1 = __shfl(h.y, gk, 8);
        const float a2 = __shfl(h.z, gk, 8);
        const float a3 = __shfl(h.w, gk, 8);
        o0 += a0 * W2s[gk * 4 + 0][c0] + a1 * W2s[gk * 4 + 1][c0]
            + a2 * W2s[gk * 4 + 2][c0] + a3 * W2s[gk * 4 + 3][c0];
        o1 += a0 * W2s[gk * 4 + 0][c0 + 1] + a1 * W2s[gk * 4 + 1][c0 + 1]
            + a2 * W2s[gk * 4 + 2][c0 + 1] + a3 * W2s[gk * 4 + 3][c0 + 1];
    }
    *(unsigned int*)(out + node * 16 + c0) = pack2(o0 * dv, o1 * dv);
}

// ---- gather D=16 (bf16) + fused linear3 -> bf16 out[N][8] ----
__global__ void gather16_lin3_kernel(const int* __restrict__ rowptr, const int* __restrict__ cnt,
                                     const int* __restrict__ list,
                                     const unsigned short* __restrict__ hs,
                                     const float* __restrict__ dinv, const float* __restrict__ b2,
                                     const float* __restrict__ W3,
                                     unsigned short* __restrict__ out, int N) {
    __shared__ float W3s[16][8];
    const int t = threadIdx.x;
    if (t < 32) ((float4*)&W3s[0][0])[t] = ((const float4*)W3)[t];
    __syncthreads();
    const int g = t >> 2, lane = t & 3;
    long node = (long)blockIdx.x * 64 + g;
    if (node >= N) return;
    const int start = rowptr[node];
    const int num = cnt[node];
    const int* __restrict__ lp = list + start;
    const uint2* __restrict__ hsv = (const uint2*)hs;
    const int L = 4;
    float4 acc = up4(hsv[node * L + lane]);
    int j = 0;
    for (; j + 8 <= num; j += 8) {
        int s0 = lp[j], s1 = lp[j + 1], s2 = lp[j + 2], s3 = lp[j + 3];
        int s4 = lp[j + 4], s5 = lp[j + 5], s6 = lp[j + 6], s7 = lp[j + 7];
        uint2 u0 = hsv[(long)s0 * L + lane], u1 = hsv[(long)s1 * L + lane];
        uint2 u2 = hsv[(long)s2 * L + lane], u3 = hsv[(long)s3 * L + lane];
        uint2 u4 = hsv[(long)s4 * L + lane], u5 = hsv[(long)s5 * L + lane];
        uint2 u6 = hsv[(long)s6 * L + lane], u7 = hsv[(long)s7 * L + lane];
        float4 v0 = up4(u0), v1 = up4(u1), v2 = up4(u2), v3 = up4(u3);
        float4 v4 = up4(u4), v5 = up4(u5), v6 = up4(u6), v7 = up4(u7);
        acc.x += ((v0.x + v1.x) + (v2.x + v3.x)) + ((v4.x + v5.x) + (v6.x + v7.x));
        acc.y += ((v0.y + v1.y) + (v2.y + v3.y)) + ((v4.y + v5.y) + (v6.y + v7.y));
        acc.z += ((v0.z + v1.z) + (v2.z + v3.z)) + ((v4.z + v5.z) + (v6.z + v7.z));
        acc.w += ((v0.w + v1.w) + (v2.w + v3.w)) + ((v4.w + v5.w) + (v6.w + v7.w));
    }
    if (j + 4 <= num) {
        int s0 = lp[j], s1 = lp[j + 1], s2 = lp[j + 2], s3 = lp[j + 3];
        uint2 u0 = hsv[(long)s0 * L + lane], u1 = hsv[(long)s1 * L + lane];
        uint2 u2 = hsv[(long)s2 * L + lane], u3 = hsv[(long)s3 * L + lane];
        float4 v0 = up4(u0), v1 = up4(u1), v2 = up4(u2), v3 = up4(u3);
        acc.x += (v0.x + v1.x) + (v2.x + v3.x);
        acc.y += (v0.y + v1.y) + (v2.y + v3.y);
        acc.z += (v0.z + v1.z) + (v2.z + v3.z);
        acc.w += (v0.w + v1.w) + (v2.w + v3.w);
        j += 4;
    }
    for (; j < num; ++j) {
        float4 v = up4(hsv[(long)lp[j] * L + lane]);
        acc.x += v.x; acc.y += v.y; acc.z += v.z; acc.w += v.w;
    }
    const float dv = dinv[node];
    const float4 bb = *(const float4*)(b2 + lane * 4);
    float4 h;
    h.x = tanhf(acc.x * dv + bb.x);
    h.y = tanhf(acc.y * dv + bb.y);
    h.z = tanhf(acc.z * dv + bb.z);
    h.w = tanhf(acc.w * dv + bb.w);
    const int c0 = lane * 2;
    float o0 = 0.f, o1 = 0.f;
#pragma unroll
    for (int gk = 0; gk < 4; ++gk) {
        const float a0 = __shfl(h.x, gk, 4);
        const float a1 = __shfl(h.y, gk, 4);
        const float a2 = __shfl(h.z, gk, 4);
        const float a3 = __shfl(h.w, gk, 4);
        o0 += a0 * W3s[gk * 4 + 0][c0] + a1 * W3s[gk * 4 + 1][c0]
            + a2 * W3s[gk * 4 + 2][c0] + a3 * W3s[gk * 4 + 3][c0];
        o1 += a0 * W3s[gk * 4 + 0][c0 + 1] + a1 * W3s[gk * 4 + 1][c0 + 1]
            + a2 * W3s[gk * 4 + 2][c0 + 1] + a3 * W3s[gk * 4 + 3][c0 + 1];
    }
    *(unsigned int*)(out + node * 8 + c0) = pack2(o0 * dv, o1 * dv);
}

// ---- gather D=8 (bf16) + classifier -> fp32 out[N][4] ----
__global__ void gather8_final_kernel(const int* __restrict__ rowptr, const int* __restrict__ cnt,
                                     const int* __restrict__ list,
                                     const unsigned short* __restrict__ hs,
                                     const float* __restrict__ dinv, const float* __restrict__ b,
                                     const float* __restrict__ Wc, const float* __restrict__ bc,
                                     float* __restrict__ out, int N) {
    const int t = threadIdx.x;
    const int g = t >> 1, lane = t & 1;
    long node = (long)blockIdx.x * 128 + g;
    if (node >= N) return;
    const int start = rowptr[node];
    const int num = cnt[node];
    const int* __restrict__ lp = list + start;
    const uint2* __restrict__ hsv = (const uint2*)hs;
    const int L = 2;
    float4 acc = up4(hsv[node * L + lane]);
    int j = 0;
    for (; j + 8 <= num; j += 8) {
        int s0 = lp[j], s1 = lp[j + 1], s2 = lp[j + 2], s3 = lp[j + 3];
        int s4 = lp[j + 4], s5 = lp[j + 5], s6 = lp[j + 6], s7 = lp[j + 7];
        uint2 u0 = hsv[(long)s0 * L + lane], u1 = hsv[(long)s1 * L + lane];
        uint2 u2 = hsv[(long)s2 * L + lane], u3 = hsv[(long)s3 * L + lane];
        uint2 u4 = hsv[(long)s4 * L + lane], u5 = hsv[(long)s5 * L + lane];
        uint2 u6 = hsv[(long)s6 * L + lane], u7 = hsv[(long)s7 * L + lane];
        float4 v0 = up4(u0), v1 = up4(u1), v2 = up4(u2), v3 = up4(u3);
        float4 v4 = up4(u4), v5 = up4(u5), v6 = up4(u6), v7 = up4(u7);
        acc.x += ((v0.x + v1.x) + (v2.x + v3.x)) + ((v4.x + v5.x) + (v6.x + v7.x));
        acc.y += ((v0.y + v1.y) + (v2.y + v3.y)) + ((v4.y + v5.y) + (v6.y + v7.y));
        acc.z += ((v0.z + v1.z) + (v2.z + v3.z)) + ((v4.z + v5.z) + (v6.z + v7.z));
        acc.w += ((v0.w + v1.w) + (v2.w + v3.w)) + ((v4.w + v5.w) + (v6.w + v7.w));
    }
    if (j + 4 <= num) {
        int s0 = lp[j], s1 = lp[j + 1], s2 = lp[j + 2], s3 = lp[j + 3];
        uint2 u0 = hsv[(long)s0 * L + lane], u1 = hsv[(long)s1 * L + lane];
        uint2 u2 = hsv[(long)s2 * L + lane], u3 = hsv[(long)s3 * L + lane];
        float4 v0 = up4(u0), v1 = up4(u1), v2 = up4(u2), v3 = up4(u3);
        acc.x += (v0.x + v1.x) + (v2.x + v3.x);
        acc.y += (v0.y + v1.y) + (v2.y + v3.y);
        acc.z += (v0.z + v1.z) + (v2.z + v3.z);
        acc.w += (v0.w + v1.w) + (v2.w + v3.w);
        j += 4;
    }
    for (; j < num; ++j) {
        float4 v = up4(hsv[(long)lp[j] * L + lane]);
        acc.x += v.x; acc.y += v.y; acc.z += v.z; acc.w += v.w;
    }
    const float dv = dinv[node];
    const float4 bb = *(const float4*)(b + lane * 4);
    float4 h;
    h.x = tanhf(acc.x * dv + bb.x);
    h.y = tanhf(acc.y * dv + bb.y);
    h.z = tanhf(acc.z * dv + bb.z);
    h.w = tanhf(acc.w * dv + bb.w);
    const float4 w0 = *(const float4*)(Wc + (lane * 4 + 0) * 4);
    const float4 w1 = *(const float4*)(Wc + (lane * 4 + 1) * 4);
    const float4 w2 = *(const float4*)(Wc + (lane * 4 + 2) * 4);
    const float4 w3 = *(const float4*)(Wc + (lane * 4 + 3) * 4);
    float4 p;
    p.x = h.x * w0.x + h.y * w1.x + h.z * w2.x + h.w * w3.x;
    p.y = h.x * w0.y + h.y * w1.y + h.z * w2.y + h.w * w3.y;
    p.z = h.x * w0.z + h.y * w1.z + h.z * w2.z + h.w * w3.z;
    p.w = h.x * w0.w + h.y * w1.w + h.z * w2.w + h.w * w3.w;
    p.x += __shfl_xor(p.x, 1);
    p.y += __shfl_xor(p.y, 1);
    p.z += __shfl_xor(p.z, 1);
    p.w += __shfl_xor(p.w, 1);
    if (lane == 0) {
        const float4 bcv = *(const float4*)bc;
        float4 o = make_float4(p.x + bcv.x, p.y + bcv.y, p.z + bcv.z, p.w + bcv.w);
        *(float4*)(out + node * 4) = o;
    }
}

extern "C" void kernel_launch(void* const* d_in, const int* in_sizes, int n_in,
                              void* d_out, int out_size, void* d_ws, size_t ws_size,
                              hipStream_t stream) {
    const float* x  = (const float*)d_in[0];
    const int*   ei = (const int*)d_in[1];
    const float* W1 = (const float*)d_in[2];
    const float* b1 = (const float*)d_in[3];
    const float* W2 = (const float*)d_in[4];
    const float* b2 = (const float*)d_in[5];
    const float* W3 = (const float*)d_in[6];
    const float* b3 = (const float*)d_in[7];
    const float* Wc = (const float*)d_in[8];
    const float* bc = (const float*)d_in[9];
    float* out = (float*)d_out;

    const int N = in_sizes[0] / F_IN;
    const int E = in_sizes[1] / 2;
    const int* src = ei;
    const int* dst = ei + E;
    const int B = 256;

    const int NB_C = (N + BN - 1) >> BSH;       // coarse buckets (196) <= 256
    const int nch  = (E + CH - 1) / CH;         // chunks (391)

    char* p = (char*)d_ws;
    auto take = [&](size_t bytes) { char* q = p; p += (bytes + 255) & ~size_t(255); return q; };
    int*   cnt     = (int*)take((size_t)N * 4);
    int*   rowptr  = (int*)take((size_t)N * 4);
    float* dinv    = (float*)take((size_t)N * 4);
    int*   hist    = (int*)take((size_t)NB_C * nch * 4);
    int*   btotal  = (int*)take((size_t)NB_C * 4);
    int*   colbase = (int*)take((size_t)(NB_C + 1) * 4);
    int*   list    = (int*)take((size_t)E * 4);
    unsigned short* bufA = (unsigned short*)take((size_t)N * 32 * 4);
    unsigned short* bufB = (unsigned short*)take((size_t)N * 32 * 4);
    int*   pairs   = (int*)bufA;   // alias: pairs dead before gather32 writes bufA

    // ---- CSR build (deterministic two-level counting sort, packed pairs) ----
    histc_kernel<<<nch, B, 0, stream>>>(dst, hist, NB_C, nch, E);
    scanb_kernel<<<NB_C, B, 0, stream>>>(hist, btotal, nch);
    scanc_kernel<<<1, B, 0, stream>>>(btotal, colbase, NB_C);
    scat_kernel<<<nch, B, 0, stream>>>(src, dst, hist, colbase, pairs, NB_C, nch, E);
    csrb_kernel<<<NB_C, 512, 0, stream>>>(pairs, colbase, cnt, rowptr, dinv, list, N);

    // ---- layer 1: 256 -> 32 (MFMA, bf16 hs) ----
    linear1_kernel<<<(N + 127) / 128, B, 0, stream>>>(x, W1, dinv, bufB, N);
    // ---- layer 1 conv + layer 2 linear fused (bf16 -> bf16) ----
    gather32_lin2_kernel<<<(N + 31) / 32, B, 0, stream>>>(rowptr, cnt, list, bufB, dinv, b1, W2, bufA, N);
    // ---- layer 2 conv + layer 3 linear fused (bf16 -> bf16) ----
    gather16_lin3_kernel<<<(N + 63) / 64, B, 0, stream>>>(rowptr, cnt, list, bufA, dinv, b2, W3, bufB, N);
    // ---- layer 3 conv + classifier fused (bf16 -> fp32 out) ----
    gather8_final_kernel<<<(N + 127) / 128, B, 0, stream>>>(rowptr, cnt, list, bufB, dinv, b3, Wc, bc, out, N);
}